// Round 8
// baseline (352.190 us; speedup 1.0000x reference)
//
#include <hip/hip_runtime.h>
#include <hip/hip_bf16.h>
#include <math.h>

// B=8, P=1024, DIM=768, H=12, KV=6, GS=2, HD=64
// R8: R7 minus the XCD swizzle (it caused correlated-stream L2 contention:
// FETCH dropped to ideal 12 MB but stalls tripled -> 169 us. L2 replication
// across XCDs is cheap; lockstep same-address streams within one XCD are not).
// Kept: static-max softmax, hoisted Q frags, bf16 Z, prep fusion, 2-ph stats.

#define NTHREADS 256

typedef __bf16 bf16x8 __attribute__((ext_vector_type(8)));
typedef float f32x4 __attribute__((ext_vector_type(4)));

#define MFMA16(a, b, c) __builtin_amdgcn_mfma_f32_16x16x32_bf16(a, b, c, 0, 0, 0)

__device__ __forceinline__ void gload16(const void* g, void* l) {
    __builtin_amdgcn_global_load_lds(
        (const __attribute__((address_space(1))) void*)g,
        (__attribute__((address_space(3))) void*)l, 16, 0, 0);
}

// ---------------- Threefry-2x32 partitionable, key=(0,42) --------------------
__device__ __forceinline__ unsigned rotl_u32(unsigned x, int r) {
    return (x << r) | (x >> (32 - r));
}
__device__ __forceinline__ void threefry_0_42(unsigned x0, unsigned x1,
                                              unsigned& o0, unsigned& o1) {
    const unsigned ks0 = 0u, ks1 = 42u, ks2 = 0u ^ 42u ^ 0x1BD11BDAu;
    x0 += ks0; x1 += ks1;
#define R4(a,b,c,d) \
    x0 += x1; x1 = rotl_u32(x1,a); x1 ^= x0; \
    x0 += x1; x1 = rotl_u32(x1,b); x1 ^= x0; \
    x0 += x1; x1 = rotl_u32(x1,c); x1 ^= x0; \
    x0 += x1; x1 = rotl_u32(x1,d); x1 ^= x0;
    R4(13,15,26,6)   x0 += ks1; x1 += ks2 + 1u;
    R4(17,29,16,24)  x0 += ks2; x1 += ks0 + 2u;
    R4(13,15,26,6)   x0 += ks0; x1 += ks1 + 3u;
    R4(17,29,16,24)  x0 += ks1; x1 += ks2 + 4u;
    R4(13,15,26,6)   x0 += ks2; x1 += ks0 + 5u;
#undef R4
    o0 = x0; o1 = x1;
}
__device__ __forceinline__ float tf_uniform(unsigned i) {
    unsigned o0, o1;
    threefry_0_42(0u, i, o0, o1);
    unsigned bits = o0 ^ o1;
    return __uint_as_float((bits >> 9) | 0x3f800000u) - 1.0f;
}

__device__ __forceinline__ float wave_sum64(float v) {
#pragma unroll
    for (int off = 32; off; off >>= 1) v += __shfl_xor(v, off, 64);
    return v;
}

__device__ __forceinline__ unsigned short bf16_rne(float x) {
    unsigned u = __float_as_uint(x);
    return (unsigned short)((u + 0x7fffu + ((u >> 16) & 1u)) >> 16);
}
__device__ __forceinline__ unsigned pack_bf16x2(float lo, float hi) {
    return (unsigned)bf16_rne(lo) | ((unsigned)bf16_rne(hi) << 16);
}
__device__ __forceinline__ float bfu(unsigned v) {
    return __uint_as_float(v << 16);
}

// ---------------- prep: cast_x | z1(bf16) | cast_w fused ---------------------
__global__ __launch_bounds__(NTHREADS) void prep_k(
    const float* __restrict__ x, const float* __restrict__ Wq,
    const float* __restrict__ Wk, const float* __restrict__ Wv,
    const float* __restrict__ Wp,
    unsigned short* __restrict__ xb, unsigned short* __restrict__ wqt,
    unsigned short* __restrict__ wkt, unsigned short* __restrict__ wvt,
    unsigned short* __restrict__ wpt,
    unsigned short* __restrict__ zb, float* __restrict__ zpart)
{
    __shared__ float rbuf[8];
    int blk = blockIdx.x;
    if (blk < 6144) {
        int i = blk * NTHREADS + threadIdx.x;
        float4 v = ((const float4*)x)[i];
        uint2 u;
        u.x = pack_bf16x2(v.x, v.y);
        u.y = pack_bf16x2(v.z, v.w);
        *(uint2*)(xb + (size_t)i * 4) = u;
    } else if (blk < 6240) {
        int bh = blk - 6144;
        int row = bh >> 3, chunk = bh & 7;
        int g = row & 1;
        int j0 = chunk * 8192;
        float sum = 0.f, sumsq = 0.f;
        for (int t = threadIdx.x; t < 8192; t += NTHREADS) {
            int j = j0 + t;
            unsigned i = (unsigned)row * 65536u + (unsigned)j;
            float m = tf_uniform(i);
            if (j == g) m = 0.f;
            zb[i] = bf16_rne(m);
            sum += m; sumsq += m * m;
        }
        sum = wave_sum64(sum); sumsq = wave_sum64(sumsq);
        int lane = threadIdx.x & 63, wv = threadIdx.x >> 6;
        if (lane == 0) { rbuf[wv] = sum; rbuf[4 + wv] = sumsq; }
        __syncthreads();
        if (threadIdx.x == 0) {
            zpart[bh * 2]     = rbuf[0] + rbuf[1] + rbuf[2] + rbuf[3];
            zpart[bh * 2 + 1] = rbuf[4] + rbuf[5] + rbuf[6] + rbuf[7];
        }
    } else {
        int id = blk - 6240;
        const float* W; unsigned short* Wt; int N;
        if (id < 144)      { W = Wq; Wt = wqt; N = 768; }
        else if (id < 216) { W = Wk; Wt = wkt; N = 384; id -= 144; }
        else if (id < 288) { W = Wv; Wt = wvt; N = 384; id -= 216; }
        else               { W = Wp; Wt = wpt; N = 768; id -= 288; }
        int ntn = N >> 6;
        int kt = id / ntn, nt = id % ntn;
        int k0 = kt * 64, n0 = nt * 64;
        int t = threadIdx.x;
        int tn = t & 63, tk = t >> 6;
        float r[16];
#pragma unroll
        for (int j = 0; j < 16; ++j)
            r[j] = W[(size_t)(k0 + tk * 16 + j) * N + n0 + tn];
        uint4 u0, u1;
        u0.x = pack_bf16x2(r[0], r[1]);   u0.y = pack_bf16x2(r[2], r[3]);
        u0.z = pack_bf16x2(r[4], r[5]);   u0.w = pack_bf16x2(r[6], r[7]);
        u1.x = pack_bf16x2(r[8], r[9]);   u1.y = pack_bf16x2(r[10], r[11]);
        u1.z = pack_bf16x2(r[12], r[13]); u1.w = pack_bf16x2(r[14], r[15]);
        unsigned short* dst = Wt + (size_t)(n0 + tn) * 768 + k0 + tk * 16;
        *(uint4*)dst = u0;
        *(uint4*)(dst + 8) = u1;
    }
}

// ---------------- bf16 MFMA GEMM core: 128x128 tile, BK=32 -------------------
__device__ __forceinline__ void mfma_tile_compute(
    const unsigned short* __restrict__ A, const unsigned short* __restrict__ Bt,
    int row0, int col0,
    unsigned short* As, unsigned short* Bs, f32x4 acc[4][4])
{
    const int tid = threadIdx.x;
    const int w = tid >> 6, lane = tid & 63;
    const int c = lane & 15, g = lane >> 4;
    const int m0 = (w & 1) * 64, n0 = (w >> 1) * 64;

#pragma unroll
    for (int mi = 0; mi < 4; ++mi)
#pragma unroll
        for (int ni = 0; ni < 4; ++ni) acc[mi][ni] = (f32x4){0.f, 0.f, 0.f, 0.f};

    const unsigned short* Ag0 = A + (size_t)(row0 + w * 16 + c) * 768 + g * 8;
    const unsigned short* Ag1 = A + (size_t)(row0 + (w + 4) * 16 + c) * 768 + g * 8;
    const unsigned short* Bg0 = Bt + (size_t)(col0 + w * 16 + c) * 768 + g * 8;
    const unsigned short* Bg1 = Bt + (size_t)(col0 + (w + 4) * 16 + c) * 768 + g * 8;
    unsigned short* Al0 = As + w * 512 + lane * 8;
    unsigned short* Al1 = As + (w + 4) * 512 + lane * 8;
    unsigned short* Bl0 = Bs + w * 512 + lane * 8;
    unsigned short* Bl1 = Bs + (w + 4) * 512 + lane * 8;

    for (int k0 = 0; k0 < 768; k0 += 32) {
        __syncthreads();
        gload16(Ag0 + k0, Al0);
        gload16(Ag1 + k0, Al1);
        gload16(Bg0 + k0, Bl0);
        gload16(Bg1 + k0, Bl1);
        __syncthreads();
        bf16x8 aA[4], bB[4];
#pragma unroll
        for (int mi = 0; mi < 4; ++mi)
            aA[mi] = *(const bf16x8*)&As[(size_t)((m0 >> 4) + mi) * 512 + g * 128 + c * 8];
#pragma unroll
        for (int ni = 0; ni < 4; ++ni)
            bB[ni] = *(const bf16x8*)&Bs[(size_t)((n0 >> 4) + ni) * 512 + g * 128 + c * 8];
#pragma unroll
        for (int mi = 0; mi < 4; ++mi)
#pragma unroll
            for (int ni = 0; ni < 4; ++ni)
                acc[mi][ni] = MFMA16(aA[mi], bB[ni], acc[mi][ni]);
    }
}

// qkv: q,k transposed orientation (rows=out-channel, cols=p); v normal.
__global__ __launch_bounds__(NTHREADS) void qkv_mfma_k(
    const unsigned short* __restrict__ xb, const unsigned short* __restrict__ wqt,
    const unsigned short* __restrict__ wkt, const unsigned short* __restrict__ wvt,
    unsigned short* __restrict__ qbh, unsigned short* __restrict__ kb2,
    unsigned short* __restrict__ vb2)
{
    __shared__ unsigned short As[4096];
    __shared__ unsigned short Bs[4096];
    int nb = blockIdx.x;
    int y0 = blockIdx.y * 128;
    f32x4 acc[4][4];

    const int tid = threadIdx.x;
    const int w = tid >> 6, lane = tid & 63;
    const int c = lane & 15, g = lane >> 4;
    const int m0 = (w & 1) * 64, n0 = (w >> 1) * 64;

    if (nb < 9) {
        int row0 = (nb < 6) ? nb * 128 : (nb - 6) * 128;
        const unsigned short* Wt = (nb < 6) ? wqt : wkt;
        mfma_tile_compute(Wt, xb, row0, y0, As, Bs, acc);
        float scale = (nb < 6) ? 0.125f : 1.0f;
#pragma unroll
        for (int mi = 0; mi < 4; ++mi) {
            int ocol = row0 + m0 + mi * 16 + g * 4;
#pragma unroll
            for (int ni = 0; ni < 4; ++ni) {
                int pglob = y0 + n0 + ni * 16 + c;
                int b = pglob >> 10, pin = pglob & 1023;
                ushort4 u;
                u.x = bf16_rne(acc[mi][ni][0] * scale);
                u.y = bf16_rne(acc[mi][ni][1] * scale);
                u.z = bf16_rne(acc[mi][ni][2] * scale);
                u.w = bf16_rne(acc[mi][ni][3] * scale);
                if (nb < 6) {
                    int h = ocol >> 6, d0 = ocol & 63;
                    *(ushort4*)&qbh[(((size_t)b * 12 + h) * 1024 + pin) * 64 + d0] = u;
                } else {
                    int kv = ocol >> 6, d0 = ocol & 63;
                    int kt = pin >> 7, key = pin & 127;
                    *(ushort4*)&kb2[((((size_t)(b * 6 + kv) * 8 + kt) * 8 + (d0 >> 3)) * 128
                                     + key) * 8 + (d0 & 7)] = u;
                }
            }
        }
    } else {
        int col0 = (nb - 9) * 128;
        mfma_tile_compute(xb, wvt, y0, col0, As, Bs, acc);
#pragma unroll
        for (int mi = 0; mi < 4; ++mi) {
            int pglob = y0 + m0 + mi * 16 + g * 4;
            int b = pglob >> 10, pin = pglob & 1023;
            int kt = pin >> 7, pg = (pin & 127) >> 3, p8 = pin & 7;
#pragma unroll
            for (int ni = 0; ni < 4; ++ni) {
                int vcol = col0 + n0 + ni * 16 + c;
                int kv = vcol >> 6, d = vcol & 63;
                ushort4 u;
                u.x = bf16_rne(acc[mi][ni][0]);
                u.y = bf16_rne(acc[mi][ni][1]);
                u.z = bf16_rne(acc[mi][ni][2]);
                u.w = bf16_rne(acc[mi][ni][3]);
                *(ushort4*)&vb2[((((size_t)(b * 6 + kv) * 8 + kt) * 16 + pg) * 64 + d) * 8 + p8] = u;
            }
        }
    }
}

// proj transposed: rows = out-cols, cols = p -> float4 stores filling lines
__global__ __launch_bounds__(NTHREADS) void proj_mfma_k(
    const unsigned short* __restrict__ attb, const unsigned short* __restrict__ wpt,
    const float* __restrict__ bp, float* __restrict__ out)
{
    __shared__ unsigned short As[4096];
    __shared__ unsigned short Bs[4096];
    int row0 = blockIdx.x * 128, col0 = blockIdx.y * 128;
    f32x4 acc[4][4];
    mfma_tile_compute(wpt, attb, row0, col0, As, Bs, acc);

    const int tid = threadIdx.x;
    const int w = tid >> 6, lane = tid & 63;
    const int c = lane & 15, g = lane >> 4;
    const int m0 = (w & 1) * 64, n0 = (w >> 1) * 64;
#pragma unroll
    for (int mi = 0; mi < 4; ++mi) {
        int ocol = row0 + m0 + mi * 16 + g * 4;
        float4 bias = *(const float4*)&bp[ocol];
#pragma unroll
        for (int ni = 0; ni < 4; ++ni) {
            int p = col0 + n0 + ni * 16 + c;
            float4 u;
            u.x = acc[mi][ni][0] + bias.x;
            u.y = acc[mi][ni][1] + bias.y;
            u.z = acc[mi][ni][2] + bias.z;
            u.w = acc[mi][ni][3] + bias.w;
            *(float4*)&out[(size_t)p * 768 + ocol] = u;
        }
    }
}

// ---------------- bf16 MFMA flash attention, 128-q tiles, natural grid -------
// grid (8 qtiles, 12 h, 8 b). Static-max softmax (logits ~N(0,1); exp safe).
#define LDP 136
__global__ __launch_bounds__(NTHREADS) void attn_mfma_k(
    const unsigned short* __restrict__ qbh, const unsigned short* __restrict__ kb2,
    const unsigned short* __restrict__ vb2, unsigned short* __restrict__ attb)
{
    __shared__ unsigned short P_lds[4 * 32 * LDP];
    __shared__ float l_s[4][32];

    const int qt0 = blockIdx.x * 128;
    const int h = blockIdx.y, b = blockIdx.z, kv = h >> 1;
    const int tid = threadIdx.x;
    const int w = tid >> 6, lane = tid & 63;
    const int c = lane & 15, g = lane >> 4;

    const unsigned short* qp = qbh + (((size_t)b * 12 + h) * 1024 + qt0 + w * 32) * 64;
    const unsigned short* kbase = kb2 + ((size_t)(b * 6 + kv) * 8) * 8192;
    const unsigned short* vbase = vb2 + ((size_t)(b * 6 + kv) * 8) * 8192;
    unsigned short* Pw = P_lds + w * 32 * LDP;

    // hoisted Q fragments [ks][qn]
    bf16x8 bQ[2][2];
    bQ[0][0] = *(const bf16x8*)(qp + (size_t)c * 64 + g * 8);
    bQ[1][0] = *(const bf16x8*)(qp + (size_t)c * 64 + 32 + g * 8);
    bQ[0][1] = *(const bf16x8*)(qp + (size_t)(16 + c) * 64 + g * 8);
    bQ[1][1] = *(const bf16x8*)(qp + (size_t)(16 + c) * 64 + 32 + g * 8);

    f32x4 O[2][4];
#pragma unroll
    for (int i = 0; i < 2; ++i)
#pragma unroll
        for (int j = 0; j < 4; ++j) O[i][j] = (f32x4){0.f, 0.f, 0.f, 0.f};
    float l_r[2] = {0.f, 0.f};

    for (int t = 0; t < 8; ++t) {
        const unsigned short* kt = kbase + (size_t)t * 8192;
        const unsigned short* vt = vbase + (size_t)t * 8192;
        f32x4 S[8][2];
#pragma unroll
        for (int mb = 0; mb < 8; ++mb) {
            S[mb][0] = (f32x4){0.f, 0.f, 0.f, 0.f};
            S[mb][1] = (f32x4){0.f, 0.f, 0.f, 0.f};
        }
#pragma unroll
        for (int ks = 0; ks < 2; ++ks) {
#pragma unroll
            for (int mb = 0; mb < 8; ++mb) {
                bf16x8 aK = *(const bf16x8*)(kt + ((size_t)(ks * 4 + g) * 128 + mb * 16 + c) * 8);
                S[mb][0] = MFMA16(aK, bQ[ks][0], S[mb][0]);
                S[mb][1] = MFMA16(aK, bQ[ks][1], S[mb][1]);
            }
        }
        // static-max softmax: P = exp(S), accumulate l
#pragma unroll
        for (int qn = 0; qn < 2; ++qn) {
            float lt = 0.f;
#pragma unroll
            for (int mb = 0; mb < 8; ++mb) {
#pragma unroll
                for (int r = 0; r < 4; ++r) {
                    float p = __expf(S[mb][qn][r]);
                    S[mb][qn][r] = p;
                    lt += p;
                }
            }
            l_r[qn] += lt;
#pragma unroll
            for (int mb = 0; mb < 8; ++mb) {
                uint2 uu;
                uu.x = pack_bf16x2(S[mb][qn][0], S[mb][qn][1]);
                uu.y = pack_bf16x2(S[mb][qn][2], S[mb][qn][3]);
                *(uint2*)&Pw[(size_t)(qn * 16 + c) * LDP + mb * 16 + g * 4] = uu;
            }
        }
        // O += P·V
#pragma unroll
        for (int ks = 0; ks < 4; ++ks) {
            bf16x8 aP0 = *(const bf16x8*)&Pw[(size_t)(c) * LDP + ks * 32 + g * 8];
            bf16x8 aP1 = *(const bf16x8*)&Pw[(size_t)(16 + c) * LDP + ks * 32 + g * 8];
#pragma unroll
            for (int nb = 0; nb < 4; ++nb) {
                bf16x8 bV = *(const bf16x8*)(vt + ((size_t)(ks * 4 + g) * 64 + nb * 16 + c) * 8);
                O[0][nb] = MFMA16(aP0, bV, O[0][nb]);
                O[1][nb] = MFMA16(aP1, bV, O[1][nb]);
            }
        }
    }
    // final l reduce (once, not per tile)
#pragma unroll
    for (int qn = 0; qn < 2; ++qn) {
        l_r[qn] += __shfl_xor(l_r[qn], 16, 64);
        l_r[qn] += __shfl_xor(l_r[qn], 32, 64);
    }
    if (g == 0) { l_s[w][c] = l_r[0]; l_s[w][16 + c] = l_r[1]; }
    f32x4 li0 = *(f32x4*)&l_s[w][g * 4];
    f32x4 li1 = *(f32x4*)&l_s[w][16 + g * 4];
    float inv0[4], inv1[4];
#pragma unroll
    for (int r = 0; r < 4; ++r) { inv0[r] = 1.f / li0[r]; inv1[r] = 1.f / li1[r]; }
    unsigned short* ob = attb + ((size_t)b * 1024 + qt0 + w * 32) * 768 + h * 64;
#pragma unroll
    for (int r = 0; r < 4; ++r) {
#pragma unroll
        for (int nb = 0; nb < 4; ++nb) {
            ob[(size_t)(g * 4 + r) * 768 + nb * 16 + c]      = bf16_rne(O[0][nb][r] * inv0[r]);
            ob[(size_t)(16 + g * 4 + r) * 768 + nb * 16 + c] = bf16_rne(O[1][nb][r] * inv1[r]);
        }
    }
}

// ---------------- stats phase 1: partial sums, 768 blocks --------------------
__global__ __launch_bounds__(NTHREADS) void stats1_k(
    const unsigned short* __restrict__ attb, float* __restrict__ spart)
{
    int blk = blockIdx.x;
    int bh = blk >> 3, ch = blk & 7;
    int b = bh / 12, h = bh % 12;
    const unsigned short* base = attb + ((size_t)b * 1024 + ch * 128) * 768 + h * 64;
    float sum = 0.f, sumsq = 0.f;
    for (int f = threadIdx.x; f < 1024; f += NTHREADS) {
        int p = f >> 3, dq = (f & 7) * 8;
        uint4 u = *(const uint4*)(base + (size_t)p * 768 + dq);
        float v0 = bfu(u.x), v1 = bfu(u.x >> 16);
        float v2 = bfu(u.y), v3 = bfu(u.y >> 16);
        float v4 = bfu(u.z), v5 = bfu(u.z >> 16);
        float v6 = bfu(u.w), v7 = bfu(u.w >> 16);
        sum   += (v0 + v1) + (v2 + v3) + (v4 + v5) + (v6 + v7);
        sumsq += (v0*v0 + v1*v1) + (v2*v2 + v3*v3) + (v4*v4 + v5*v5) + (v6*v6 + v7*v7);
    }
    __shared__ float rbuf[8];
    sum = wave_sum64(sum); sumsq = wave_sum64(sumsq);
    int lane = threadIdx.x & 63, wv = threadIdx.x >> 6;
    if (lane == 0) { rbuf[wv] = sum; rbuf[4 + wv] = sumsq; }
    __syncthreads();
    if (threadIdx.x == 0) {
        spart[blk * 2]     = rbuf[0] + rbuf[1] + rbuf[2] + rbuf[3];
        spart[blk * 2 + 1] = rbuf[4] + rbuf[5] + rbuf[6] + rbuf[7];
    }
}

// ---------------- stats phase 2: att -= M*a - b (Z in bf16) ------------------
__global__ __launch_bounds__(NTHREADS) void stats2_k(
    unsigned short* __restrict__ attb, const unsigned short* __restrict__ zb,
    const float* __restrict__ spart, const float* __restrict__ zpart)
{
    int blk = blockIdx.x;
    int bh = blk >> 3, ch = blk & 7;
    int b = bh / 12, h = bh % 12;
    float zs = 0.f, zs2 = 0.f, rs = 0.f, rs2 = 0.f;
#pragma unroll
    for (int cc = 0; cc < 8; ++cc) {
        zs  += zpart[(h * 8 + cc) * 2];
        zs2 += zpart[(h * 8 + cc) * 2 + 1];
        rs  += spart[(bh * 8 + cc) * 2];
        rs2 += spart[(bh * 8 + cc) * 2 + 1];
    }
    float m_mean = zs * (1.f / 65536.f);
    float m_var  = (zs2 - 65536.f * m_mean * m_mean) * (1.f / 65535.f);
    float m_sd   = sqrtf(fmaxf(m_var, 0.f));
    if (m_sd == 0.f) m_sd = 1.f;
    float r_mean = rs * (1.f / 65536.f);
    float r_var  = (rs2 - 65536.f * r_mean * r_mean) * (1.f / 65535.f);
    float r_sd   = sqrtf(fmaxf(r_var, 0.f));
    float a = r_sd / m_sd;
    float bc = m_mean * a - r_mean;

    unsigned short* base = attb + ((size_t)b * 1024 + ch * 128) * 768 + h * 64;
    const unsigned short* zrow = zb + (size_t)h * 65536 + (size_t)ch * 8192;
    for (int f = threadIdx.x; f < 1024; f += NTHREADS) {
        int p = f >> 3, dq = (f & 7) * 8;
        unsigned short* ptr = base + (size_t)p * 768 + dq;
        uint4 u = *(const uint4*)ptr;
        uint4 zu = *(const uint4*)(zrow + (size_t)f * 8);
        float v0 = bfu(u.x)       - bfu(zu.x)       * a + bc;
        float v1 = bfu(u.x >> 16) - bfu(zu.x >> 16) * a + bc;
        float v2 = bfu(u.y)       - bfu(zu.y)       * a + bc;
        float v3 = bfu(u.y >> 16) - bfu(zu.y >> 16) * a + bc;
        float v4 = bfu(u.z)       - bfu(zu.z)       * a + bc;
        float v5 = bfu(u.z >> 16) - bfu(zu.z >> 16) * a + bc;
        float v6 = bfu(u.w)       - bfu(zu.w)       * a + bc;
        float v7 = bfu(u.w >> 16) - bfu(zu.w >> 16) * a + bc;
        uint4 o;
        o.x = pack_bf16x2(v0, v1);
        o.y = pack_bf16x2(v2, v3);
        o.z = pack_bf16x2(v4, v5);
        o.w = pack_bf16x2(v6, v7);
        *(uint4*)ptr = o;
    }
}

extern "C" void kernel_launch(void* const* d_in, const int* in_sizes, int n_in,
                              void* d_out, int out_size, void* d_ws, size_t ws_size,
                              hipStream_t stream) {
    const float* x  = (const float*)d_in[0];
    const float* Wq = (const float*)d_in[1];
    const float* Wk = (const float*)d_in[2];
    const float* Wv = (const float*)d_in[3];
    const float* Wp = (const float*)d_in[4];
    const float* bp = (const float*)d_in[5];
    float* out = (float*)d_out;

    float* ws    = (float*)d_ws;
    float* zpart = ws;                    // 192 f
    float* spart = zpart + 192;           // 1536 f
    unsigned short* zb   = (unsigned short*)(spart + 1536);  // 786432 us (bf16 M)
    unsigned short* xb   = zb + 786432;    // 6291456
    unsigned short* wqt  = xb + 6291456;   // 589824
    unsigned short* wkt  = wqt + 589824;   // 294912
    unsigned short* wvt  = wkt + 294912;   // 294912
    unsigned short* wpt  = wvt + 294912;   // 589824
    unsigned short* qbh  = wpt + 589824;   // 6291456
    unsigned short* kb2  = qbh + 6291456;  // 3145728
    unsigned short* vb2  = kb2 + 3145728;  // 3145728
    unsigned short* attb = vb2 + 3145728;  // 6291456

    prep_k<<<6672, NTHREADS, 0, stream>>>(x, Wq, Wk, Wv, Wp,
                                          xb, wqt, wkt, wvt, wpt, zb, zpart);
    qkv_mfma_k<<<dim3(12, 64), NTHREADS, 0, stream>>>(xb, wqt, wkt, wvt, qbh, kb2, vb2);
    attn_mfma_k<<<dim3(8, 12, 8), NTHREADS, 0, stream>>>(qbh, kb2, vb2, attb);
    stats1_k<<<768, NTHREADS, 0, stream>>>(attb, spart);
    stats2_k<<<768, NTHREADS, 0, stream>>>(attb, zb, spart, zpart);
    proj_mfma_k<<<dim3(6, 64), NTHREADS, 0, stream>>>(attb, wpt, bp, out);
}

// Round 9
// 244.577 us; speedup vs baseline: 1.4400x; 1.4400x over previous
//
#include <hip/hip_runtime.h>
#include <hip/hip_bf16.h>
#include <math.h>

// B=8, P=1024, DIM=768, H=12, KV=6, GS=2, HD=64
// R9: attn reverted to R5's exact kernel (64.6 us measured). R7/R8's
// "static-max softmax + hoisted Q" caused a 3x stall regression at constant
// MFMA/VALU busy-time (robust to XCD swizzle on/off) -- scheduler pathology,
// not locality. Peripherals keep the R6/R8 wins: fused prep, 2-phase stats,
// bf16 Z.

#define NTHREADS 256

typedef __bf16 bf16x8 __attribute__((ext_vector_type(8)));
typedef float f32x4 __attribute__((ext_vector_type(4)));

#define MFMA16(a, b, c) __builtin_amdgcn_mfma_f32_16x16x32_bf16(a, b, c, 0, 0, 0)

__device__ __forceinline__ void gload16(const void* g, void* l) {
    __builtin_amdgcn_global_load_lds(
        (const __attribute__((address_space(1))) void*)g,
        (__attribute__((address_space(3))) void*)l, 16, 0, 0);
}

// ---------------- Threefry-2x32 partitionable, key=(0,42) --------------------
__device__ __forceinline__ unsigned rotl_u32(unsigned x, int r) {
    return (x << r) | (x >> (32 - r));
}
__device__ __forceinline__ void threefry_0_42(unsigned x0, unsigned x1,
                                              unsigned& o0, unsigned& o1) {
    const unsigned ks0 = 0u, ks1 = 42u, ks2 = 0u ^ 42u ^ 0x1BD11BDAu;
    x0 += ks0; x1 += ks1;
#define R4(a,b,c,d) \
    x0 += x1; x1 = rotl_u32(x1,a); x1 ^= x0; \
    x0 += x1; x1 = rotl_u32(x1,b); x1 ^= x0; \
    x0 += x1; x1 = rotl_u32(x1,c); x1 ^= x0; \
    x0 += x1; x1 = rotl_u32(x1,d); x1 ^= x0;
    R4(13,15,26,6)   x0 += ks1; x1 += ks2 + 1u;
    R4(17,29,16,24)  x0 += ks2; x1 += ks0 + 2u;
    R4(13,15,26,6)   x0 += ks0; x1 += ks1 + 3u;
    R4(17,29,16,24)  x0 += ks1; x1 += ks2 + 4u;
    R4(13,15,26,6)   x0 += ks2; x1 += ks0 + 5u;
#undef R4
    o0 = x0; o1 = x1;
}
__device__ __forceinline__ float tf_uniform(unsigned i) {
    unsigned o0, o1;
    threefry_0_42(0u, i, o0, o1);
    unsigned bits = o0 ^ o1;
    return __uint_as_float((bits >> 9) | 0x3f800000u) - 1.0f;
}

__device__ __forceinline__ float wave_sum64(float v) {
#pragma unroll
    for (int off = 32; off; off >>= 1) v += __shfl_xor(v, off, 64);
    return v;
}

__device__ __forceinline__ unsigned short bf16_rne(float x) {
    unsigned u = __float_as_uint(x);
    return (unsigned short)((u + 0x7fffu + ((u >> 16) & 1u)) >> 16);
}
__device__ __forceinline__ unsigned pack_bf16x2(float lo, float hi) {
    return (unsigned)bf16_rne(lo) | ((unsigned)bf16_rne(hi) << 16);
}
__device__ __forceinline__ float bfu(unsigned v) {
    return __uint_as_float(v << 16);
}

// ---------------- prep: cast_x | z1(bf16) | cast_w fused ---------------------
__global__ __launch_bounds__(NTHREADS) void prep_k(
    const float* __restrict__ x, const float* __restrict__ Wq,
    const float* __restrict__ Wk, const float* __restrict__ Wv,
    const float* __restrict__ Wp,
    unsigned short* __restrict__ xb, unsigned short* __restrict__ wqt,
    unsigned short* __restrict__ wkt, unsigned short* __restrict__ wvt,
    unsigned short* __restrict__ wpt,
    unsigned short* __restrict__ zb, float* __restrict__ zpart)
{
    __shared__ float rbuf[8];
    int blk = blockIdx.x;
    if (blk < 6144) {
        int i = blk * NTHREADS + threadIdx.x;
        float4 v = ((const float4*)x)[i];
        uint2 u;
        u.x = pack_bf16x2(v.x, v.y);
        u.y = pack_bf16x2(v.z, v.w);
        *(uint2*)(xb + (size_t)i * 4) = u;
    } else if (blk < 6240) {
        int bh = blk - 6144;
        int row = bh >> 3, chunk = bh & 7;
        int g = row & 1;
        int j0 = chunk * 8192;
        float sum = 0.f, sumsq = 0.f;
        for (int t = threadIdx.x; t < 8192; t += NTHREADS) {
            int j = j0 + t;
            unsigned i = (unsigned)row * 65536u + (unsigned)j;
            float m = tf_uniform(i);
            if (j == g) m = 0.f;
            zb[i] = bf16_rne(m);
            sum += m; sumsq += m * m;
        }
        sum = wave_sum64(sum); sumsq = wave_sum64(sumsq);
        int lane = threadIdx.x & 63, wv = threadIdx.x >> 6;
        if (lane == 0) { rbuf[wv] = sum; rbuf[4 + wv] = sumsq; }
        __syncthreads();
        if (threadIdx.x == 0) {
            zpart[bh * 2]     = rbuf[0] + rbuf[1] + rbuf[2] + rbuf[3];
            zpart[bh * 2 + 1] = rbuf[4] + rbuf[5] + rbuf[6] + rbuf[7];
        }
    } else {
        int id = blk - 6240;
        const float* W; unsigned short* Wt; int N;
        if (id < 144)      { W = Wq; Wt = wqt; N = 768; }
        else if (id < 216) { W = Wk; Wt = wkt; N = 384; id -= 144; }
        else if (id < 288) { W = Wv; Wt = wvt; N = 384; id -= 216; }
        else               { W = Wp; Wt = wpt; N = 768; id -= 288; }
        int ntn = N >> 6;
        int kt = id / ntn, nt = id % ntn;
        int k0 = kt * 64, n0 = nt * 64;
        int t = threadIdx.x;
        int tn = t & 63, tk = t >> 6;
        float r[16];
#pragma unroll
        for (int j = 0; j < 16; ++j)
            r[j] = W[(size_t)(k0 + tk * 16 + j) * N + n0 + tn];
        uint4 u0, u1;
        u0.x = pack_bf16x2(r[0], r[1]);   u0.y = pack_bf16x2(r[2], r[3]);
        u0.z = pack_bf16x2(r[4], r[5]);   u0.w = pack_bf16x2(r[6], r[7]);
        u1.x = pack_bf16x2(r[8], r[9]);   u1.y = pack_bf16x2(r[10], r[11]);
        u1.z = pack_bf16x2(r[12], r[13]); u1.w = pack_bf16x2(r[14], r[15]);
        unsigned short* dst = Wt + (size_t)(n0 + tn) * 768 + k0 + tk * 16;
        *(uint4*)dst = u0;
        *(uint4*)(dst + 8) = u1;
    }
}

// ---------------- bf16 MFMA GEMM core: 128x128 tile, BK=32 -------------------
__device__ __forceinline__ void mfma_tile_compute(
    const unsigned short* __restrict__ A, const unsigned short* __restrict__ Bt,
    int row0, int col0,
    unsigned short* As, unsigned short* Bs, f32x4 acc[4][4])
{
    const int tid = threadIdx.x;
    const int w = tid >> 6, lane = tid & 63;
    const int c = lane & 15, g = lane >> 4;
    const int m0 = (w & 1) * 64, n0 = (w >> 1) * 64;

#pragma unroll
    for (int mi = 0; mi < 4; ++mi)
#pragma unroll
        for (int ni = 0; ni < 4; ++ni) acc[mi][ni] = (f32x4){0.f, 0.f, 0.f, 0.f};

    const unsigned short* Ag0 = A + (size_t)(row0 + w * 16 + c) * 768 + g * 8;
    const unsigned short* Ag1 = A + (size_t)(row0 + (w + 4) * 16 + c) * 768 + g * 8;
    const unsigned short* Bg0 = Bt + (size_t)(col0 + w * 16 + c) * 768 + g * 8;
    const unsigned short* Bg1 = Bt + (size_t)(col0 + (w + 4) * 16 + c) * 768 + g * 8;
    unsigned short* Al0 = As + w * 512 + lane * 8;
    unsigned short* Al1 = As + (w + 4) * 512 + lane * 8;
    unsigned short* Bl0 = Bs + w * 512 + lane * 8;
    unsigned short* Bl1 = Bs + (w + 4) * 512 + lane * 8;

    for (int k0 = 0; k0 < 768; k0 += 32) {
        __syncthreads();
        gload16(Ag0 + k0, Al0);
        gload16(Ag1 + k0, Al1);
        gload16(Bg0 + k0, Bl0);
        gload16(Bg1 + k0, Bl1);
        __syncthreads();
        bf16x8 aA[4], bB[4];
#pragma unroll
        for (int mi = 0; mi < 4; ++mi)
            aA[mi] = *(const bf16x8*)&As[(size_t)((m0 >> 4) + mi) * 512 + g * 128 + c * 8];
#pragma unroll
        for (int ni = 0; ni < 4; ++ni)
            bB[ni] = *(const bf16x8*)&Bs[(size_t)((n0 >> 4) + ni) * 512 + g * 128 + c * 8];
#pragma unroll
        for (int mi = 0; mi < 4; ++mi)
#pragma unroll
            for (int ni = 0; ni < 4; ++ni)
                acc[mi][ni] = MFMA16(aA[mi], bB[ni], acc[mi][ni]);
    }
}

// qkv: q,k transposed orientation (rows=out-channel, cols=p); v normal.
__global__ __launch_bounds__(NTHREADS) void qkv_mfma_k(
    const unsigned short* __restrict__ xb, const unsigned short* __restrict__ wqt,
    const unsigned short* __restrict__ wkt, const unsigned short* __restrict__ wvt,
    unsigned short* __restrict__ qbh, unsigned short* __restrict__ kb2,
    unsigned short* __restrict__ vb2)
{
    __shared__ unsigned short As[4096];
    __shared__ unsigned short Bs[4096];
    int nb = blockIdx.x;
    int y0 = blockIdx.y * 128;
    f32x4 acc[4][4];

    const int tid = threadIdx.x;
    const int w = tid >> 6, lane = tid & 63;
    const int c = lane & 15, g = lane >> 4;
    const int m0 = (w & 1) * 64, n0 = (w >> 1) * 64;

    if (nb < 9) {
        int row0 = (nb < 6) ? nb * 128 : (nb - 6) * 128;
        const unsigned short* Wt = (nb < 6) ? wqt : wkt;
        mfma_tile_compute(Wt, xb, row0, y0, As, Bs, acc);
        float scale = (nb < 6) ? 0.125f : 1.0f;
#pragma unroll
        for (int mi = 0; mi < 4; ++mi) {
            int ocol = row0 + m0 + mi * 16 + g * 4;
#pragma unroll
            for (int ni = 0; ni < 4; ++ni) {
                int pglob = y0 + n0 + ni * 16 + c;
                int b = pglob >> 10, pin = pglob & 1023;
                ushort4 u;
                u.x = bf16_rne(acc[mi][ni][0] * scale);
                u.y = bf16_rne(acc[mi][ni][1] * scale);
                u.z = bf16_rne(acc[mi][ni][2] * scale);
                u.w = bf16_rne(acc[mi][ni][3] * scale);
                if (nb < 6) {
                    int h = ocol >> 6, d0 = ocol & 63;
                    *(ushort4*)&qbh[(((size_t)b * 12 + h) * 1024 + pin) * 64 + d0] = u;
                } else {
                    int kv = ocol >> 6, d0 = ocol & 63;
                    int kt = pin >> 7, key = pin & 127;
                    *(ushort4*)&kb2[((((size_t)(b * 6 + kv) * 8 + kt) * 8 + (d0 >> 3)) * 128
                                     + key) * 8 + (d0 & 7)] = u;
                }
            }
        }
    } else {
        int col0 = (nb - 9) * 128;
        mfma_tile_compute(xb, wvt, y0, col0, As, Bs, acc);
#pragma unroll
        for (int mi = 0; mi < 4; ++mi) {
            int pglob = y0 + m0 + mi * 16 + g * 4;
            int b = pglob >> 10, pin = pglob & 1023;
            int kt = pin >> 7, pg = (pin & 127) >> 3, p8 = pin & 7;
#pragma unroll
            for (int ni = 0; ni < 4; ++ni) {
                int vcol = col0 + n0 + ni * 16 + c;
                int kv = vcol >> 6, d = vcol & 63;
                ushort4 u;
                u.x = bf16_rne(acc[mi][ni][0]);
                u.y = bf16_rne(acc[mi][ni][1]);
                u.z = bf16_rne(acc[mi][ni][2]);
                u.w = bf16_rne(acc[mi][ni][3]);
                *(ushort4*)&vb2[((((size_t)(b * 6 + kv) * 8 + kt) * 16 + pg) * 64 + d) * 8 + p8] = u;
            }
        }
    }
}

// proj transposed: rows = out-cols, cols = p -> float4 stores filling lines
__global__ __launch_bounds__(NTHREADS) void proj_mfma_k(
    const unsigned short* __restrict__ attb, const unsigned short* __restrict__ wpt,
    const float* __restrict__ bp, float* __restrict__ out)
{
    __shared__ unsigned short As[4096];
    __shared__ unsigned short Bs[4096];
    int row0 = blockIdx.x * 128, col0 = blockIdx.y * 128;
    f32x4 acc[4][4];
    mfma_tile_compute(wpt, attb, row0, col0, As, Bs, acc);

    const int tid = threadIdx.x;
    const int w = tid >> 6, lane = tid & 63;
    const int c = lane & 15, g = lane >> 4;
    const int m0 = (w & 1) * 64, n0 = (w >> 1) * 64;
#pragma unroll
    for (int mi = 0; mi < 4; ++mi) {
        int ocol = row0 + m0 + mi * 16 + g * 4;
        float4 bias = *(const float4*)&bp[ocol];
#pragma unroll
        for (int ni = 0; ni < 4; ++ni) {
            int p = col0 + n0 + ni * 16 + c;
            float4 u;
            u.x = acc[mi][ni][0] + bias.x;
            u.y = acc[mi][ni][1] + bias.y;
            u.z = acc[mi][ni][2] + bias.z;
            u.w = acc[mi][ni][3] + bias.w;
            *(float4*)&out[(size_t)p * 768 + ocol] = u;
        }
    }
}

// ---------------- bf16 MFMA flash attention (R5 verbatim) --------------------
// K from kb2 [b][kv][kt][d/8][key128][8], V from vb2 [b][kv][kt][key/8][d64][8]
#define LDP 136
__global__ __launch_bounds__(NTHREADS) void attn_mfma_k(
    const unsigned short* __restrict__ qbh, const unsigned short* __restrict__ kb2,
    const unsigned short* __restrict__ vb2, unsigned short* __restrict__ attb)
{
    __shared__ unsigned short P_lds[4 * 32 * LDP];
    __shared__ float alpha_s[4][32];
    __shared__ float l_s[4][32];

    const int qt0 = blockIdx.x * 128;
    const int h = blockIdx.y, b = blockIdx.z, kv = h >> 1;
    const int tid = threadIdx.x;
    const int w = tid >> 6, lane = tid & 63;
    const int c = lane & 15, g = lane >> 4;

    const unsigned short* qh = qbh + (((size_t)b * 12 + h) * 1024 + qt0 + w * 32) * 64;
    const unsigned short* kbase = kb2 + ((size_t)(b * 6 + kv) * 8) * 8192;
    const unsigned short* vbase = vb2 + ((size_t)(b * 6 + kv) * 8) * 8192;
    unsigned short* Pw = P_lds + w * 32 * LDP;

    f32x4 O[2][4];
#pragma unroll
    for (int i = 0; i < 2; ++i)
#pragma unroll
        for (int j = 0; j < 4; ++j) O[i][j] = (f32x4){0.f, 0.f, 0.f, 0.f};
    float m_r[2] = {-1e30f, -1e30f};
    float l_r[2] = {0.f, 0.f};

    for (int t = 0; t < 8; ++t) {
        const unsigned short* kt = kbase + (size_t)t * 8192;
        const unsigned short* vt = vbase + (size_t)t * 8192;
        f32x4 S[8][2];
#pragma unroll
        for (int mb = 0; mb < 8; ++mb) {
            S[mb][0] = (f32x4){0.f, 0.f, 0.f, 0.f};
            S[mb][1] = (f32x4){0.f, 0.f, 0.f, 0.f};
        }
#pragma unroll
        for (int ks = 0; ks < 2; ++ks) {
            bf16x8 bQ0 = *(const bf16x8*)(qh + (size_t)(c) * 64 + ks * 32 + g * 8);
            bf16x8 bQ1 = *(const bf16x8*)(qh + (size_t)(16 + c) * 64 + ks * 32 + g * 8);
#pragma unroll
            for (int mb = 0; mb < 8; ++mb) {
                bf16x8 aK = *(const bf16x8*)(kt + ((size_t)(ks * 4 + g) * 128 + mb * 16 + c) * 8);
                S[mb][0] = MFMA16(aK, bQ0, S[mb][0]);
                S[mb][1] = MFMA16(aK, bQ1, S[mb][1]);
            }
        }
#pragma unroll
        for (int qn = 0; qn < 2; ++qn) {
            float mt = -1e30f;
#pragma unroll
            for (int mb = 0; mb < 8; ++mb)
#pragma unroll
                for (int r = 0; r < 4; ++r) mt = fmaxf(mt, S[mb][qn][r]);
            mt = fmaxf(mt, __shfl_xor(mt, 16, 64));
            mt = fmaxf(mt, __shfl_xor(mt, 32, 64));
            float mnew = fmaxf(m_r[qn], mt);
            float alpha = __expf(m_r[qn] - mnew);
            float lt = 0.f;
#pragma unroll
            for (int mb = 0; mb < 8; ++mb) {
#pragma unroll
                for (int r = 0; r < 4; ++r) {
                    float p = __expf(S[mb][qn][r] - mnew);
                    S[mb][qn][r] = p;
                    lt += p;
                }
            }
            lt += __shfl_xor(lt, 16, 64);
            lt += __shfl_xor(lt, 32, 64);
            l_r[qn] = l_r[qn] * alpha + lt;
            m_r[qn] = mnew;
            if (g == 0) alpha_s[w][qn * 16 + c] = alpha;
#pragma unroll
            for (int mb = 0; mb < 8; ++mb) {
                uint2 uu;
                uu.x = pack_bf16x2(S[mb][qn][0], S[mb][qn][1]);
                uu.y = pack_bf16x2(S[mb][qn][2], S[mb][qn][3]);
                *(uint2*)&Pw[(size_t)(qn * 16 + c) * LDP + mb * 16 + g * 4] = uu;
            }
        }
        f32x4 al0 = *(f32x4*)&alpha_s[w][g * 4];
        f32x4 al1 = *(f32x4*)&alpha_s[w][16 + g * 4];
#pragma unroll
        for (int nb = 0; nb < 4; ++nb)
#pragma unroll
            for (int r = 0; r < 4; ++r) {
                O[0][nb][r] *= al0[r];
                O[1][nb][r] *= al1[r];
            }
#pragma unroll
        for (int ks = 0; ks < 4; ++ks) {
            bf16x8 aP0 = *(const bf16x8*)&Pw[(size_t)(c) * LDP + ks * 32 + g * 8];
            bf16x8 aP1 = *(const bf16x8*)&Pw[(size_t)(16 + c) * LDP + ks * 32 + g * 8];
#pragma unroll
            for (int nb = 0; nb < 4; ++nb) {
                bf16x8 bV = *(const bf16x8*)(vt + ((size_t)(ks * 4 + g) * 64 + nb * 16 + c) * 8);
                O[0][nb] = MFMA16(aP0, bV, O[0][nb]);
                O[1][nb] = MFMA16(aP1, bV, O[1][nb]);
            }
        }
    }
    if (g == 0) { l_s[w][c] = l_r[0]; l_s[w][16 + c] = l_r[1]; }
    f32x4 li0 = *(f32x4*)&l_s[w][g * 4];
    f32x4 li1 = *(f32x4*)&l_s[w][16 + g * 4];
    float inv0[4], inv1[4];
#pragma unroll
    for (int r = 0; r < 4; ++r) { inv0[r] = 1.f / li0[r]; inv1[r] = 1.f / li1[r]; }
    unsigned short* ob = attb + ((size_t)b * 1024 + qt0 + w * 32) * 768 + h * 64;
#pragma unroll
    for (int r = 0; r < 4; ++r) {
#pragma unroll
        for (int nb = 0; nb < 4; ++nb) {
            ob[(size_t)(g * 4 + r) * 768 + nb * 16 + c]      = bf16_rne(O[0][nb][r] * inv0[r]);
            ob[(size_t)(16 + g * 4 + r) * 768 + nb * 16 + c] = bf16_rne(O[1][nb][r] * inv1[r]);
        }
    }
}

// ---------------- stats phase 1: partial sums, 768 blocks --------------------
__global__ __launch_bounds__(NTHREADS) void stats1_k(
    const unsigned short* __restrict__ attb, float* __restrict__ spart)
{
    int blk = blockIdx.x;
    int bh = blk >> 3, ch = blk & 7;
    int b = bh / 12, h = bh % 12;
    const unsigned short* base = attb + ((size_t)b * 1024 + ch * 128) * 768 + h * 64;
    float sum = 0.f, sumsq = 0.f;
    for (int f = threadIdx.x; f < 1024; f += NTHREADS) {
        int p = f >> 3, dq = (f & 7) * 8;
        uint4 u = *(const uint4*)(base + (size_t)p * 768 + dq);
        float v0 = bfu(u.x), v1 = bfu(u.x >> 16);
        float v2 = bfu(u.y), v3 = bfu(u.y >> 16);
        float v4 = bfu(u.z), v5 = bfu(u.z >> 16);
        float v6 = bfu(u.w), v7 = bfu(u.w >> 16);
        sum   += (v0 + v1) + (v2 + v3) + (v4 + v5) + (v6 + v7);
        sumsq += (v0*v0 + v1*v1) + (v2*v2 + v3*v3) + (v4*v4 + v5*v5) + (v6*v6 + v7*v7);
    }
    __shared__ float rbuf[8];
    sum = wave_sum64(sum); sumsq = wave_sum64(sumsq);
    int lane = threadIdx.x & 63, wv = threadIdx.x >> 6;
    if (lane == 0) { rbuf[wv] = sum; rbuf[4 + wv] = sumsq; }
    __syncthreads();
    if (threadIdx.x == 0) {
        spart[blk * 2]     = rbuf[0] + rbuf[1] + rbuf[2] + rbuf[3];
        spart[blk * 2 + 1] = rbuf[4] + rbuf[5] + rbuf[6] + rbuf[7];
    }
}

// ---------------- stats phase 2: att -= M*a - b (Z in bf16) ------------------
__global__ __launch_bounds__(NTHREADS) void stats2_k(
    unsigned short* __restrict__ attb, const unsigned short* __restrict__ zb,
    const float* __restrict__ spart, const float* __restrict__ zpart)
{
    int blk = blockIdx.x;
    int bh = blk >> 3, ch = blk & 7;
    int b = bh / 12, h = bh % 12;
    float zs = 0.f, zs2 = 0.f, rs = 0.f, rs2 = 0.f;
#pragma unroll
    for (int cc = 0; cc < 8; ++cc) {
        zs  += zpart[(h * 8 + cc) * 2];
        zs2 += zpart[(h * 8 + cc) * 2 + 1];
        rs  += spart[(bh * 8 + cc) * 2];
        rs2 += spart[(bh * 8 + cc) * 2 + 1];
    }
    float m_mean = zs * (1.f / 65536.f);
    float m_var  = (zs2 - 65536.f * m_mean * m_mean) * (1.f / 65535.f);
    float m_sd   = sqrtf(fmaxf(m_var, 0.f));
    if (m_sd == 0.f) m_sd = 1.f;
    float r_mean = rs * (1.f / 65536.f);
    float r_var  = (rs2 - 65536.f * r_mean * r_mean) * (1.f / 65535.f);
    float r_sd   = sqrtf(fmaxf(r_var, 0.f));
    float a = r_sd / m_sd;
    float bc = m_mean * a - r_mean;

    unsigned short* base = attb + ((size_t)b * 1024 + ch * 128) * 768 + h * 64;
    const unsigned short* zrow = zb + (size_t)h * 65536 + (size_t)ch * 8192;
    for (int f = threadIdx.x; f < 1024; f += NTHREADS) {
        int p = f >> 3, dq = (f & 7) * 8;
        unsigned short* ptr = base + (size_t)p * 768 + dq;
        uint4 u = *(const uint4*)ptr;
        uint4 zu = *(const uint4*)(zrow + (size_t)f * 8);
        float v0 = bfu(u.x)       - bfu(zu.x)       * a + bc;
        float v1 = bfu(u.x >> 16) - bfu(zu.x >> 16) * a + bc;
        float v2 = bfu(u.y)       - bfu(zu.y)       * a + bc;
        float v3 = bfu(u.y >> 16) - bfu(zu.y >> 16) * a + bc;
        float v4 = bfu(u.z)       - bfu(zu.z)       * a + bc;
        float v5 = bfu(u.z >> 16) - bfu(zu.z >> 16) * a + bc;
        float v6 = bfu(u.w)       - bfu(zu.w)       * a + bc;
        float v7 = bfu(u.w >> 16) - bfu(zu.w >> 16) * a + bc;
        uint4 o;
        o.x = pack_bf16x2(v0, v1);
        o.y = pack_bf16x2(v2, v3);
        o.z = pack_bf16x2(v4, v5);
        o.w = pack_bf16x2(v6, v7);
        *(uint4*)ptr = o;
    }
}

extern "C" void kernel_launch(void* const* d_in, const int* in_sizes, int n_in,
                              void* d_out, int out_size, void* d_ws, size_t ws_size,
                              hipStream_t stream) {
    const float* x  = (const float*)d_in[0];
    const float* Wq = (const float*)d_in[1];
    const float* Wk = (const float*)d_in[2];
    const float* Wv = (const float*)d_in[3];
    const float* Wp = (const float*)d_in[4];
    const float* bp = (const float*)d_in[5];
    float* out = (float*)d_out;

    float* ws    = (float*)d_ws;
    float* zpart = ws;                    // 192 f
    float* spart = zpart + 192;           // 1536 f
    unsigned short* zb   = (unsigned short*)(spart + 1536);  // 786432 us (bf16 M)
    unsigned short* xb   = zb + 786432;    // 6291456
    unsigned short* wqt  = xb + 6291456;   // 589824
    unsigned short* wkt  = wqt + 589824;   // 294912
    unsigned short* wvt  = wkt + 294912;   // 294912
    unsigned short* wpt  = wvt + 294912;   // 589824
    unsigned short* qbh  = wpt + 589824;   // 6291456
    unsigned short* kb2  = qbh + 6291456;  // 3145728
    unsigned short* vb2  = kb2 + 3145728;  // 3145728
    unsigned short* attb = vb2 + 3145728;  // 6291456

    prep_k<<<6672, NTHREADS, 0, stream>>>(x, Wq, Wk, Wv, Wp,
                                          xb, wqt, wkt, wvt, wpt, zb, zpart);
    qkv_mfma_k<<<dim3(12, 64), NTHREADS, 0, stream>>>(xb, wqt, wkt, wvt, qbh, kb2, vb2);
    attn_mfma_k<<<dim3(8, 12, 8), NTHREADS, 0, stream>>>(qbh, kb2, vb2, attb);
    stats1_k<<<768, NTHREADS, 0, stream>>>(attb, spart);
    stats2_k<<<768, NTHREADS, 0, stream>>>(attb, zb, spart, zpart);
    proj_mfma_k<<<dim3(6, 64), NTHREADS, 0, stream>>>(attb, wpt, bp, out);
}

// Round 10
// 239.870 us; speedup vs baseline: 1.4683x; 1.0196x over previous
//
#include <hip/hip_runtime.h>
#include <hip/hip_bf16.h>
#include <math.h>

// B=8, P=1024, DIM=768, H=12, KV=6, GS=2, HD=64
// R10: attn = R5 structure + exp2-folded scale + fused stats1 epilogue.
// GEMMs: BK=64 (half the barriers). prep: fatter x-cast blocks, Z over 384
// blocks. 5 kernels: prep, qkv, attn(+stats1), stats2, proj.

#define NTHREADS 256

typedef __bf16 bf16x8 __attribute__((ext_vector_type(8)));
typedef float f32x4 __attribute__((ext_vector_type(4)));

#define MFMA16(a, b, c) __builtin_amdgcn_mfma_f32_16x16x32_bf16(a, b, c, 0, 0, 0)

// q scale with log2(e) folded: softmax exp(x) == exp2(x') for pre-scaled logits
#define QSCALE 0.18033688011112042f   // 0.125 * 1.4426950408889634

__device__ __forceinline__ float fexp2(float x) {
#if __has_builtin(__builtin_amdgcn_exp2f)
    return __builtin_amdgcn_exp2f(x);
#else
    return __expf(x * 0.6931471805599453f);
#endif
}

__device__ __forceinline__ void gload16(const void* g, void* l) {
    __builtin_amdgcn_global_load_lds(
        (const __attribute__((address_space(1))) void*)g,
        (__attribute__((address_space(3))) void*)l, 16, 0, 0);
}

// ---------------- Threefry-2x32 partitionable, key=(0,42) --------------------
__device__ __forceinline__ unsigned rotl_u32(unsigned x, int r) {
    return (x << r) | (x >> (32 - r));
}
__device__ __forceinline__ void threefry_0_42(unsigned x0, unsigned x1,
                                              unsigned& o0, unsigned& o1) {
    const unsigned ks0 = 0u, ks1 = 42u, ks2 = 0u ^ 42u ^ 0x1BD11BDAu;
    x0 += ks0; x1 += ks1;
#define R4(a,b,c,d) \
    x0 += x1; x1 = rotl_u32(x1,a); x1 ^= x0; \
    x0 += x1; x1 = rotl_u32(x1,b); x1 ^= x0; \
    x0 += x1; x1 = rotl_u32(x1,c); x1 ^= x0; \
    x0 += x1; x1 = rotl_u32(x1,d); x1 ^= x0;
    R4(13,15,26,6)   x0 += ks1; x1 += ks2 + 1u;
    R4(17,29,16,24)  x0 += ks2; x1 += ks0 + 2u;
    R4(13,15,26,6)   x0 += ks0; x1 += ks1 + 3u;
    R4(17,29,16,24)  x0 += ks1; x1 += ks2 + 4u;
    R4(13,15,26,6)   x0 += ks2; x1 += ks0 + 5u;
#undef R4
    o0 = x0; o1 = x1;
}
__device__ __forceinline__ float tf_uniform(unsigned i) {
    unsigned o0, o1;
    threefry_0_42(0u, i, o0, o1);
    unsigned bits = o0 ^ o1;
    return __uint_as_float((bits >> 9) | 0x3f800000u) - 1.0f;
}

__device__ __forceinline__ float wave_sum64(float v) {
#pragma unroll
    for (int off = 32; off; off >>= 1) v += __shfl_xor(v, off, 64);
    return v;
}

__device__ __forceinline__ unsigned short bf16_rne(float x) {
    unsigned u = __float_as_uint(x);
    return (unsigned short)((u + 0x7fffu + ((u >> 16) & 1u)) >> 16);
}
__device__ __forceinline__ unsigned pack_bf16x2(float lo, float hi) {
    return (unsigned)bf16_rne(lo) | ((unsigned)bf16_rne(hi) << 16);
}
__device__ __forceinline__ float bfu(unsigned v) {
    return __uint_as_float(v << 16);
}

// ---------------- prep: cast_x | z1(bf16) | cast_w fused ---------------------
// blocks [0,1536): x->bf16 (4 float4/thread); [1536,1920): Z (12 rows x 32
// chunks of 2048); [1920,2352): W casts.
__global__ __launch_bounds__(NTHREADS) void prep_k(
    const float* __restrict__ x, const float* __restrict__ Wq,
    const float* __restrict__ Wk, const float* __restrict__ Wv,
    const float* __restrict__ Wp,
    unsigned short* __restrict__ xb, unsigned short* __restrict__ wqt,
    unsigned short* __restrict__ wkt, unsigned short* __restrict__ wvt,
    unsigned short* __restrict__ wpt,
    unsigned short* __restrict__ zb, float* __restrict__ zpart)
{
    __shared__ float rbuf[8];
    int blk = blockIdx.x;
    if (blk < 1536) {
#pragma unroll
        for (int j = 0; j < 4; ++j) {
            int i = blk * 1024 + j * 256 + threadIdx.x;
            float4 v = ((const float4*)x)[i];
            uint2 u;
            u.x = pack_bf16x2(v.x, v.y);
            u.y = pack_bf16x2(v.z, v.w);
            *(uint2*)(xb + (size_t)i * 4) = u;
        }
    } else if (blk < 1920) {
        int zc = blk - 1536;
        int row = zc >> 5, chunk = zc & 31;
        int g = row & 1;
        int j0 = chunk * 2048;
        float sum = 0.f, sumsq = 0.f;
        for (int t = threadIdx.x; t < 2048; t += NTHREADS) {
            int j = j0 + t;
            unsigned i = (unsigned)row * 65536u + (unsigned)j;
            float m = tf_uniform(i);
            if (j == g) m = 0.f;
            zb[i] = bf16_rne(m);
            sum += m; sumsq += m * m;
        }
        sum = wave_sum64(sum); sumsq = wave_sum64(sumsq);
        int lane = threadIdx.x & 63, wv = threadIdx.x >> 6;
        if (lane == 0) { rbuf[wv] = sum; rbuf[4 + wv] = sumsq; }
        __syncthreads();
        if (threadIdx.x == 0) {
            zpart[zc * 2]     = rbuf[0] + rbuf[1] + rbuf[2] + rbuf[3];
            zpart[zc * 2 + 1] = rbuf[4] + rbuf[5] + rbuf[6] + rbuf[7];
        }
    } else {
        int id = blk - 1920;
        const float* W; unsigned short* Wt; int N;
        if (id < 144)      { W = Wq; Wt = wqt; N = 768; }
        else if (id < 216) { W = Wk; Wt = wkt; N = 384; id -= 144; }
        else if (id < 288) { W = Wv; Wt = wvt; N = 384; id -= 216; }
        else               { W = Wp; Wt = wpt; N = 768; id -= 288; }
        int ntn = N >> 6;
        int kt = id / ntn, nt = id % ntn;
        int k0 = kt * 64, n0 = nt * 64;
        int t = threadIdx.x;
        int tn = t & 63, tk = t >> 6;
        float r[16];
#pragma unroll
        for (int j = 0; j < 16; ++j)
            r[j] = W[(size_t)(k0 + tk * 16 + j) * N + n0 + tn];
        uint4 u0, u1;
        u0.x = pack_bf16x2(r[0], r[1]);   u0.y = pack_bf16x2(r[2], r[3]);
        u0.z = pack_bf16x2(r[4], r[5]);   u0.w = pack_bf16x2(r[6], r[7]);
        u1.x = pack_bf16x2(r[8], r[9]);   u1.y = pack_bf16x2(r[10], r[11]);
        u1.z = pack_bf16x2(r[12], r[13]); u1.w = pack_bf16x2(r[14], r[15]);
        unsigned short* dst = Wt + (size_t)(n0 + tn) * 768 + k0 + tk * 16;
        *(uint4*)dst = u0;
        *(uint4*)(dst + 8) = u1;
    }
}

// ---------------- bf16 MFMA GEMM core: 128x128 tile, BK=64 -------------------
// LDS per matrix: [chunk16(8)][khalf(2)][laneorder 512] = 16 KB.
__device__ __forceinline__ void mfma_tile_compute(
    const unsigned short* __restrict__ A, const unsigned short* __restrict__ Bt,
    int row0, int col0,
    unsigned short* As, unsigned short* Bs, f32x4 acc[4][4])
{
    const int tid = threadIdx.x;
    const int w = tid >> 6, lane = tid & 63;
    const int c = lane & 15, g = lane >> 4;
    const int m0 = (w & 1) * 64, n0 = (w >> 1) * 64;

#pragma unroll
    for (int mi = 0; mi < 4; ++mi)
#pragma unroll
        for (int ni = 0; ni < 4; ++ni) acc[mi][ni] = (f32x4){0.f, 0.f, 0.f, 0.f};

    const unsigned short* Ag0 = A + (size_t)(row0 + w * 16 + c) * 768 + g * 8;
    const unsigned short* Ag1 = A + (size_t)(row0 + (w + 4) * 16 + c) * 768 + g * 8;
    const unsigned short* Bg0 = Bt + (size_t)(col0 + w * 16 + c) * 768 + g * 8;
    const unsigned short* Bg1 = Bt + (size_t)(col0 + (w + 4) * 16 + c) * 768 + g * 8;
    unsigned short* Al0 = As + w * 1024 + lane * 8;
    unsigned short* Al1 = As + (w + 4) * 1024 + lane * 8;
    unsigned short* Bl0 = Bs + w * 1024 + lane * 8;
    unsigned short* Bl1 = Bs + (w + 4) * 1024 + lane * 8;

    for (int k0 = 0; k0 < 768; k0 += 64) {
        __syncthreads();
        gload16(Ag0 + k0,      Al0);
        gload16(Ag0 + k0 + 32, Al0 + 512);
        gload16(Ag1 + k0,      Al1);
        gload16(Ag1 + k0 + 32, Al1 + 512);
        gload16(Bg0 + k0,      Bl0);
        gload16(Bg0 + k0 + 32, Bl0 + 512);
        gload16(Bg1 + k0,      Bl1);
        gload16(Bg1 + k0 + 32, Bl1 + 512);
        __syncthreads();
#pragma unroll
        for (int ks = 0; ks < 2; ++ks) {
            bf16x8 aA[4], bB[4];
#pragma unroll
            for (int mi = 0; mi < 4; ++mi)
                aA[mi] = *(const bf16x8*)&As[(size_t)((m0 >> 4) + mi) * 1024 + ks * 512 + g * 128 + c * 8];
#pragma unroll
            for (int ni = 0; ni < 4; ++ni)
                bB[ni] = *(const bf16x8*)&Bs[(size_t)((n0 >> 4) + ni) * 1024 + ks * 512 + g * 128 + c * 8];
#pragma unroll
            for (int mi = 0; mi < 4; ++mi)
#pragma unroll
                for (int ni = 0; ni < 4; ++ni)
                    acc[mi][ni] = MFMA16(aA[mi], bB[ni], acc[mi][ni]);
        }
    }
}

// qkv: q,k transposed orientation (rows=out-channel, cols=p); v normal.
__global__ __launch_bounds__(NTHREADS) void qkv_mfma_k(
    const unsigned short* __restrict__ xb, const unsigned short* __restrict__ wqt,
    const unsigned short* __restrict__ wkt, const unsigned short* __restrict__ wvt,
    unsigned short* __restrict__ qbh, unsigned short* __restrict__ kb2,
    unsigned short* __restrict__ vb2)
{
    __shared__ unsigned short As[8192];
    __shared__ unsigned short Bs[8192];
    int nb = blockIdx.x;
    int y0 = blockIdx.y * 128;
    f32x4 acc[4][4];

    const int tid = threadIdx.x;
    const int w = tid >> 6, lane = tid & 63;
    const int c = lane & 15, g = lane >> 4;
    const int m0 = (w & 1) * 64, n0 = (w >> 1) * 64;

    if (nb < 9) {
        int row0 = (nb < 6) ? nb * 128 : (nb - 6) * 128;
        const unsigned short* Wt = (nb < 6) ? wqt : wkt;
        mfma_tile_compute(Wt, xb, row0, y0, As, Bs, acc);
        float scale = (nb < 6) ? QSCALE : 1.0f;   // log2e folded into q
#pragma unroll
        for (int mi = 0; mi < 4; ++mi) {
            int ocol = row0 + m0 + mi * 16 + g * 4;
#pragma unroll
            for (int ni = 0; ni < 4; ++ni) {
                int pglob = y0 + n0 + ni * 16 + c;
                int b = pglob >> 10, pin = pglob & 1023;
                ushort4 u;
                u.x = bf16_rne(acc[mi][ni][0] * scale);
                u.y = bf16_rne(acc[mi][ni][1] * scale);
                u.z = bf16_rne(acc[mi][ni][2] * scale);
                u.w = bf16_rne(acc[mi][ni][3] * scale);
                if (nb < 6) {
                    int h = ocol >> 6, d0 = ocol & 63;
                    *(ushort4*)&qbh[(((size_t)b * 12 + h) * 1024 + pin) * 64 + d0] = u;
                } else {
                    int kv = ocol >> 6, d0 = ocol & 63;
                    int kt = pin >> 7, key = pin & 127;
                    *(ushort4*)&kb2[((((size_t)(b * 6 + kv) * 8 + kt) * 8 + (d0 >> 3)) * 128
                                     + key) * 8 + (d0 & 7)] = u;
                }
            }
        }
    } else {
        int col0 = (nb - 9) * 128;
        mfma_tile_compute(xb, wvt, y0, col0, As, Bs, acc);
#pragma unroll
        for (int mi = 0; mi < 4; ++mi) {
            int pglob = y0 + m0 + mi * 16 + g * 4;
            int b = pglob >> 10, pin = pglob & 1023;
            int kt = pin >> 7, pg = (pin & 127) >> 3, p8 = pin & 7;
#pragma unroll
            for (int ni = 0; ni < 4; ++ni) {
                int vcol = col0 + n0 + ni * 16 + c;
                int kv = vcol >> 6, d = vcol & 63;
                ushort4 u;
                u.x = bf16_rne(acc[mi][ni][0]);
                u.y = bf16_rne(acc[mi][ni][1]);
                u.z = bf16_rne(acc[mi][ni][2]);
                u.w = bf16_rne(acc[mi][ni][3]);
                *(ushort4*)&vb2[((((size_t)(b * 6 + kv) * 8 + kt) * 16 + pg) * 64 + d) * 8 + p8] = u;
            }
        }
    }
}

// proj transposed: rows = out-cols, cols = p -> float4 stores filling lines
__global__ __launch_bounds__(NTHREADS) void proj_mfma_k(
    const unsigned short* __restrict__ attb, const unsigned short* __restrict__ wpt,
    const float* __restrict__ bp, float* __restrict__ out)
{
    __shared__ unsigned short As[8192];
    __shared__ unsigned short Bs[8192];
    int row0 = blockIdx.x * 128, col0 = blockIdx.y * 128;
    f32x4 acc[4][4];
    mfma_tile_compute(wpt, attb, row0, col0, As, Bs, acc);

    const int tid = threadIdx.x;
    const int w = tid >> 6, lane = tid & 63;
    const int c = lane & 15, g = lane >> 4;
    const int m0 = (w & 1) * 64, n0 = (w >> 1) * 64;
#pragma unroll
    for (int mi = 0; mi < 4; ++mi) {
        int ocol = row0 + m0 + mi * 16 + g * 4;
        float4 bias = *(const float4*)&bp[ocol];
#pragma unroll
        for (int ni = 0; ni < 4; ++ni) {
            int p = col0 + n0 + ni * 16 + c;
            float4 u;
            u.x = acc[mi][ni][0] + bias.x;
            u.y = acc[mi][ni][1] + bias.y;
            u.z = acc[mi][ni][2] + bias.z;
            u.w = acc[mi][ni][3] + bias.w;
            *(float4*)&out[(size_t)p * 768 + ocol] = u;
        }
    }
}

// ---------------- bf16 MFMA flash attention (R5 structure) -------------------
// exp2 softmax (scale pre-folded in q) + fused stats1 partial sums in epilogue.
#define LDP 136
__global__ __launch_bounds__(NTHREADS) void attn_mfma_k(
    const unsigned short* __restrict__ qbh, const unsigned short* __restrict__ kb2,
    const unsigned short* __restrict__ vb2, unsigned short* __restrict__ attb,
    float* __restrict__ spart)
{
    __shared__ unsigned short P_lds[4 * 32 * LDP];
    __shared__ float alpha_s[4][32];
    __shared__ float l_s[4][32];
    __shared__ float sbuf[8];

    const int qt0 = blockIdx.x * 128;
    const int h = blockIdx.y, b = blockIdx.z, kv = h >> 1;
    const int tid = threadIdx.x;
    const int w = tid >> 6, lane = tid & 63;
    const int c = lane & 15, g = lane >> 4;

    const unsigned short* qh = qbh + (((size_t)b * 12 + h) * 1024 + qt0 + w * 32) * 64;
    const unsigned short* kbase = kb2 + ((size_t)(b * 6 + kv) * 8) * 8192;
    const unsigned short* vbase = vb2 + ((size_t)(b * 6 + kv) * 8) * 8192;
    unsigned short* Pw = P_lds + w * 32 * LDP;

    f32x4 O[2][4];
#pragma unroll
    for (int i = 0; i < 2; ++i)
#pragma unroll
        for (int j = 0; j < 4; ++j) O[i][j] = (f32x4){0.f, 0.f, 0.f, 0.f};
    float m_r[2] = {-1e30f, -1e30f};
    float l_r[2] = {0.f, 0.f};

    for (int t = 0; t < 8; ++t) {
        const unsigned short* kt = kbase + (size_t)t * 8192;
        const unsigned short* vt = vbase + (size_t)t * 8192;
        f32x4 S[8][2];
#pragma unroll
        for (int mb = 0; mb < 8; ++mb) {
            S[mb][0] = (f32x4){0.f, 0.f, 0.f, 0.f};
            S[mb][1] = (f32x4){0.f, 0.f, 0.f, 0.f};
        }
#pragma unroll
        for (int ks = 0; ks < 2; ++ks) {
            bf16x8 bQ0 = *(const bf16x8*)(qh + (size_t)(c) * 64 + ks * 32 + g * 8);
            bf16x8 bQ1 = *(const bf16x8*)(qh + (size_t)(16 + c) * 64 + ks * 32 + g * 8);
#pragma unroll
            for (int mb = 0; mb < 8; ++mb) {
                bf16x8 aK = *(const bf16x8*)(kt + ((size_t)(ks * 4 + g) * 128 + mb * 16 + c) * 8);
                S[mb][0] = MFMA16(aK, bQ0, S[mb][0]);
                S[mb][1] = MFMA16(aK, bQ1, S[mb][1]);
            }
        }
#pragma unroll
        for (int qn = 0; qn < 2; ++qn) {
            float mt = -1e30f;
#pragma unroll
            for (int mb = 0; mb < 8; ++mb)
#pragma unroll
                for (int r = 0; r < 4; ++r) mt = fmaxf(mt, S[mb][qn][r]);
            mt = fmaxf(mt, __shfl_xor(mt, 16, 64));
            mt = fmaxf(mt, __shfl_xor(mt, 32, 64));
            float mnew = fmaxf(m_r[qn], mt);
            float alpha = fexp2(m_r[qn] - mnew);
            float lt = 0.f;
#pragma unroll
            for (int mb = 0; mb < 8; ++mb) {
#pragma unroll
                for (int r = 0; r < 4; ++r) {
                    float p = fexp2(S[mb][qn][r] - mnew);
                    S[mb][qn][r] = p;
                    lt += p;
                }
            }
            lt += __shfl_xor(lt, 16, 64);
            lt += __shfl_xor(lt, 32, 64);
            l_r[qn] = l_r[qn] * alpha + lt;
            m_r[qn] = mnew;
            if (g == 0) alpha_s[w][qn * 16 + c] = alpha;
#pragma unroll
            for (int mb = 0; mb < 8; ++mb) {
                uint2 uu;
                uu.x = pack_bf16x2(S[mb][qn][0], S[mb][qn][1]);
                uu.y = pack_bf16x2(S[mb][qn][2], S[mb][qn][3]);
                *(uint2*)&Pw[(size_t)(qn * 16 + c) * LDP + mb * 16 + g * 4] = uu;
            }
        }
        f32x4 al0 = *(f32x4*)&alpha_s[w][g * 4];
        f32x4 al1 = *(f32x4*)&alpha_s[w][16 + g * 4];
#pragma unroll
        for (int nb = 0; nb < 4; ++nb)
#pragma unroll
            for (int r = 0; r < 4; ++r) {
                O[0][nb][r] *= al0[r];
                O[1][nb][r] *= al1[r];
            }
#pragma unroll
        for (int ks = 0; ks < 4; ++ks) {
            bf16x8 aP0 = *(const bf16x8*)&Pw[(size_t)(c) * LDP + ks * 32 + g * 8];
            bf16x8 aP1 = *(const bf16x8*)&Pw[(size_t)(16 + c) * LDP + ks * 32 + g * 8];
#pragma unroll
            for (int nb = 0; nb < 4; ++nb) {
                bf16x8 bV = *(const bf16x8*)(vt + ((size_t)(ks * 4 + g) * 64 + nb * 16 + c) * 8);
                O[0][nb] = MFMA16(aP0, bV, O[0][nb]);
                O[1][nb] = MFMA16(aP1, bV, O[1][nb]);
            }
        }
    }
    if (g == 0) { l_s[w][c] = l_r[0]; l_s[w][16 + c] = l_r[1]; }
    f32x4 li0 = *(f32x4*)&l_s[w][g * 4];
    f32x4 li1 = *(f32x4*)&l_s[w][16 + g * 4];
    float inv0[4], inv1[4];
#pragma unroll
    for (int r = 0; r < 4; ++r) { inv0[r] = 1.f / li0[r]; inv1[r] = 1.f / li1[r]; }
    unsigned short* ob = attb + ((size_t)b * 1024 + qt0 + w * 32) * 768 + h * 64;
    float psum = 0.f, psumsq = 0.f;
#pragma unroll
    for (int r = 0; r < 4; ++r) {
#pragma unroll
        for (int nb = 0; nb < 4; ++nb) {
            float o0 = O[0][nb][r] * inv0[r];
            float o1 = O[1][nb][r] * inv1[r];
            psum += o0 + o1;
            psumsq += o0 * o0 + o1 * o1;
            ob[(size_t)(g * 4 + r) * 768 + nb * 16 + c]      = bf16_rne(o0);
            ob[(size_t)(16 + g * 4 + r) * 768 + nb * 16 + c] = bf16_rne(o1);
        }
    }
    // fused stats1: this block covers exactly (b, h, qt0..qt0+127)
    psum = wave_sum64(psum); psumsq = wave_sum64(psumsq);
    if (lane == 0) { sbuf[w] = psum; sbuf[4 + w] = psumsq; }
    __syncthreads();
    if (tid == 0) {
        int idx = ((b * 12 + h) * 8 + blockIdx.x) * 2;
        spart[idx]     = sbuf[0] + sbuf[1] + sbuf[2] + sbuf[3];
        spart[idx + 1] = sbuf[4] + sbuf[5] + sbuf[6] + sbuf[7];
    }
}

// ---------------- stats phase 2: att -= M*a - b (Z in bf16) ------------------
__global__ __launch_bounds__(NTHREADS) void stats2_k(
    unsigned short* __restrict__ attb, const unsigned short* __restrict__ zb,
    const float* __restrict__ spart, const float* __restrict__ zpart)
{
    int blk = blockIdx.x;
    int bh = blk >> 3, ch = blk & 7;
    int b = bh / 12, h = bh % 12;
    float zs = 0.f, zs2 = 0.f, rs = 0.f, rs2 = 0.f;
#pragma unroll
    for (int cc = 0; cc < 32; ++cc) {
        zs  += zpart[(h * 32 + cc) * 2];
        zs2 += zpart[(h * 32 + cc) * 2 + 1];
    }
#pragma unroll
    for (int cc = 0; cc < 8; ++cc) {
        rs  += spart[(bh * 8 + cc) * 2];
        rs2 += spart[(bh * 8 + cc) * 2 + 1];
    }
    float m_mean = zs * (1.f / 65536.f);
    float m_var  = (zs2 - 65536.f * m_mean * m_mean) * (1.f / 65535.f);
    float m_sd   = sqrtf(fmaxf(m_var, 0.f));
    if (m_sd == 0.f) m_sd = 1.f;
    float r_mean = rs * (1.f / 65536.f);
    float r_var  = (rs2 - 65536.f * r_mean * r_mean) * (1.f / 65535.f);
    float r_sd   = sqrtf(fmaxf(r_var, 0.f));
    float a = r_sd / m_sd;
    float bc = m_mean * a - r_mean;

    unsigned short* base = attb + ((size_t)b * 1024 + ch * 128) * 768 + h * 64;
    const unsigned short* zrow = zb + (size_t)h * 65536 + (size_t)ch * 8192;
    for (int f = threadIdx.x; f < 1024; f += NTHREADS) {
        int p = f >> 3, dq = (f & 7) * 8;
        unsigned short* ptr = base + (size_t)p * 768 + dq;
        uint4 u = *(const uint4*)ptr;
        uint4 zu = *(const uint4*)(zrow + (size_t)f * 8);
        float v0 = bfu(u.x)       - bfu(zu.x)       * a + bc;
        float v1 = bfu(u.x >> 16) - bfu(zu.x >> 16) * a + bc;
        float v2 = bfu(u.y)       - bfu(zu.y)       * a + bc;
        float v3 = bfu(u.y >> 16) - bfu(zu.y >> 16) * a + bc;
        float v4 = bfu(u.z)       - bfu(zu.z)       * a + bc;
        float v5 = bfu(u.z >> 16) - bfu(zu.z >> 16) * a + bc;
        float v6 = bfu(u.w)       - bfu(zu.w)       * a + bc;
        float v7 = bfu(u.w >> 16) - bfu(zu.w >> 16) * a + bc;
        uint4 o;
        o.x = pack_bf16x2(v0, v1);
        o.y = pack_bf16x2(v2, v3);
        o.z = pack_bf16x2(v4, v5);
        o.w = pack_bf16x2(v6, v7);
        *(uint4*)ptr = o;
    }
}

extern "C" void kernel_launch(void* const* d_in, const int* in_sizes, int n_in,
                              void* d_out, int out_size, void* d_ws, size_t ws_size,
                              hipStream_t stream) {
    const float* x  = (const float*)d_in[0];
    const float* Wq = (const float*)d_in[1];
    const float* Wk = (const float*)d_in[2];
    const float* Wv = (const float*)d_in[3];
    const float* Wp = (const float*)d_in[4];
    const float* bp = (const float*)d_in[5];
    float* out = (float*)d_out;

    float* ws    = (float*)d_ws;
    float* zpart = ws;                    // 768 f (12 rows x 32 chunks x 2)
    float* spart = zpart + 768;           // 1536 f
    unsigned short* zb   = (unsigned short*)(spart + 1536);  // 786432 us
    unsigned short* xb   = zb + 786432;    // 6291456
    unsigned short* wqt  = xb + 6291456;   // 589824
    unsigned short* wkt  = wqt + 589824;   // 294912
    unsigned short* wvt  = wkt + 294912;   // 294912
    unsigned short* wpt  = wvt + 294912;   // 589824
    unsigned short* qbh  = wpt + 589824;   // 6291456
    unsigned short* kb2  = qbh + 6291456;  // 3145728
    unsigned short* vb2  = kb2 + 3145728;  // 3145728
    unsigned short* attb = vb2 + 3145728;  // 6291456

    prep_k<<<2352, NTHREADS, 0, stream>>>(x, Wq, Wk, Wv, Wp,
                                          xb, wqt, wkt, wvt, wpt, zb, zpart);
    qkv_mfma_k<<<dim3(12, 64), NTHREADS, 0, stream>>>(xb, wqt, wkt, wvt, qbh, kb2, vb2);
    attn_mfma_k<<<dim3(8, 12, 8), NTHREADS, 0, stream>>>(qbh, kb2, vb2, attb, spart);
    stats2_k<<<768, NTHREADS, 0, stream>>>(attb, zb, spart, zpart);
    proj_mfma_k<<<dim3(6, 64), NTHREADS, 0, stream>>>(attb, wpt, bp, out);
}